// Round 12
// baseline (42.861 us; speedup 1.0000x reference)
//
#include <hip/hip_runtime.h>
#include <math.h>

#define PI_F 3.14159265358979323846f

// ---- 16-lane sum reduction entirely on the VALU pipe via DPP ----
// (HW-validated R7/R8/R11)
template <int CTRL>
__device__ __forceinline__ float dpp_addf(float v) {
  int p = __builtin_amdgcn_update_dpp(0, __float_as_int(v), CTRL, 0xF, 0xF, true);
  return v + __int_as_float(p);
}
__device__ __forceinline__ float red16(float v) {
  v = dpp_addf<0xB1>(v);    // quad_perm xor1
  v = dpp_addf<0x4E>(v);    // quad_perm xor2
  v = dpp_addf<0x124>(v);   // row_ror:4
  v = dpp_addf<0x128>(v);   // row_ror:8
  return v;
}

__device__ __forceinline__ void gload_lds16(const float* g, float* l) {
  __builtin_amdgcn_global_load_lds(
      (const __attribute__((address_space(1))) void*)g,
      (__attribute__((address_space(3))) void*)l, 16, 0, 0);
}

// Kernel 1: Zernike pooling. One block per (batch, rank): 32 ch x 256 px.
// = round-11 best (36.2us) EXCEPT staging is global_load_lds DMA (no ds_write,
// no VGPR round-trip) into a pixel-quad layout lds[cg][p] (float4 = 4 channels
// of one pixel), row stride 288 float4 = 1152 words (= 0 mod 32 -> compute
// reads land at bank 4*sl+sub: exactly 2-way, free).
__global__ __launch_bounds__(256) void zpool_kernel(const float* __restrict__ x,
                                                    float* __restrict__ pooled) {
  const int blk = blockIdx.x;              // 0..3071
  const int b = blk / 3;
  const int rank = blk - b * 3;
  const float* __restrict__ src = x + (size_t)b * 24576 + rank * 32;

  __shared__ float lds[8 * 1152];          // 36 KB
  const int t = threadIdx.x;
  const int lane = t & 63;
  const int w = t >> 6;                    // wave 0..3

  // Stage via DMA: slot s = t + 256*i (float4 units); slot -> (cg = s/288,
  // p = s%288, pad slots clamped). LDS dest = wave-uniform base + lane*16B
  // (R6-validated pattern); global src per-lane = p*384B + cg*16B.
#pragma unroll
  for (int i = 0; i < 9; ++i) {
    const int s = t + i * 256;             // 0..2303
    const int cg = s / 288;                // channel quad 0..7
    const int p = (s - cg * 288) & 255;    // pixel (pad slots load dup data)
    gload_lds16(src + p * 96 + cg * 4, &lds[(w * 64 + 256 * i) * 4]);
  }
  __syncthreads();

  const int sub = lane >> 4;               // 0..3 (channel within quad)
  const int sl = lane & 15;                // pixel column (w-coord)
  const float X = -1.0f + (float)sl * (2.0f / 15.0f);   // lane-constant

#pragma unroll
  for (int g = 0; g < 2; ++g) {
    const int cg = w * 2 + g;              // channel quad 0..7
    const int ch = cg * 4 + sub;           // 0..31
    const float* base = &lds[cg * 1152 + sl * 4 + sub];
    float f[16];
#pragma unroll
    for (int k = 0; k < 16; ++k) f[k] = base[64 * k];   // pixel p = sl + 16k

    // Pass 1: centroid sums. X constant per lane -> sx = X * s0.
    float s0 = 0.0f, sy = 0.0f;
#pragma unroll
    for (int k = 0; k < 16; ++k) {
      const float Y = -1.0f + (float)k * (2.0f / 15.0f);
      s0 += f[k];
      sy = fmaf(f[k], Y, sy);
    }
    float sx = X * s0;
    s0 = red16(s0); sx = red16(sx); sy = red16(sy);
    const float invm = 1.0f / (s0 + 1e-6f);
    const float cx = sx * invm;
    const float cy = sy * invm;

    const float Xs = X - cx;
    const float Xs2 = Xs * Xs;
    const float Xs3 = Xs2 * Xs;
    const float lim = 1.0f - Xs2;          // mask: Ys^2 <= 1 - Xs^2

    // Pass 2: 4 moment accumulators m_j = sum g * Ys^j (validated R7/R10/R11).
    float m0 = 0.0f, m1 = 0.0f, m2 = 0.0f, m3 = 0.0f;
#pragma unroll
    for (int k = 0; k < 16; ++k) {
      const float Y = -1.0f + (float)k * (2.0f / 15.0f);
      const float Ys = Y - cy;
      const float Ys2 = Ys * Ys;
      const float gv = (Ys2 <= lim) ? f[k] : 0.0f;
      const float gy = gv * Ys;
      m0 += gv;
      m1 += gy;
      m2 = fmaf(gy, Ys, m2);
      m3 = fmaf(gy, Ys2, m3);
    }

    // Derive the 10 raw sums S_ij = Xs^i * m_j (lane-local; Xs lane-constant).
    float S00 = m0;
    float S10 = Xs * m0;
    float S20 = Xs2 * m0;
    float S30 = Xs3 * m0;
    float S01 = m1;
    float S11 = Xs * m1;
    float S21 = Xs2 * m1;
    float S02 = m2;
    float S12 = Xs * m2;
    float S03 = m3;

    S00 = red16(S00); S10 = red16(S10); S20 = red16(S20); S30 = red16(S30);
    S01 = red16(S01); S11 = red16(S11); S21 = red16(S21);
    S02 = red16(S02); S12 = red16(S12); S03 = red16(S03);

    if (sl == 0) {
      const float a0 = S00;
      const float a1 = S10, b1 = S01;
      const float a2 = 2.0f * (S20 + S02) - S00;
      const float a3 = S20 - S02, b3 = 2.0f * S11;
      const float a4 = 3.0f * (S30 + S12) - 2.0f * S10;
      const float b4 = 3.0f * (S21 + S03) - 2.0f * S01;
      const float a5 = S30 - 3.0f * S12;
      const float b5 = 3.0f * S21 - S03;
      float* po = pooled + (size_t)b * 576 + rank * 192 + ch;
      const float INV = 1.0f / 65536.0f;    // (1/256)^2 for the means
      po[0]   = (1.0f / PI_F) * sqrtf(a0 * a0 * INV + 1e-12f);
      po[32]  = (2.0f / PI_F) * sqrtf(fmaf(a1, a1, b1 * b1) * INV + 1e-12f);
      po[64]  = (3.0f / PI_F) * sqrtf(a2 * a2 * INV + 1e-12f);
      po[96]  = (3.0f / PI_F) * sqrtf(fmaf(a3, a3, b3 * b3) * INV + 1e-12f);
      po[128] = (4.0f / PI_F) * sqrtf(fmaf(a4, a4, b4 * b4) * INV + 1e-12f);
      po[160] = (4.0f / PI_F) * sqrtf(fmaf(a5, a5, b5 * b5) * INV + 1e-12f);
    }
  }
}

// Kernel 2: batch-norm stats per feature; fold into scale a and shift c.
// (576-block version -- part of all winning packages; do NOT swap)
__global__ __launch_bounds__(256) void bn_stats_kernel(const float* __restrict__ pooled,
                                                       const float* __restrict__ gamma,
                                                       const float* __restrict__ beta,
                                                       float* __restrict__ a,
                                                       float* __restrict__ c) {
  const int f = blockIdx.x;   // 0..575
  const int t = threadIdx.x;  // 256
  float s = 0.0f, sq = 0.0f;
#pragma unroll
  for (int j = 0; j < 4; ++j) {
    const float v = pooled[(size_t)(t + 256 * j) * 576 + f];
    s += v;
    sq = fmaf(v, v, sq);
  }
#pragma unroll
  for (int m = 1; m < 64; m <<= 1) {
    s += __shfl_xor(s, m);
    sq += __shfl_xor(sq, m);
  }
  __shared__ float ls[8];
  const int w = t >> 6;
  if ((t & 63) == 0) { ls[w * 2] = s; ls[w * 2 + 1] = sq; }
  __syncthreads();
  if (t == 0) {
    s = ls[0] + ls[2] + ls[4] + ls[6];
    sq = ls[1] + ls[3] + ls[5] + ls[7];
    const float mean = s * (1.0f / 1024.0f);
    const float var = fmaf(-mean, mean, sq * (1.0f / 1024.0f));  // biased var
    const float istd = rsqrtf(var + 1e-5f);
    const float av = gamma[f] * istd;
    a[f] = av;
    c[f] = fmaf(-mean, av, beta[f]);
  }
}

// Kernel 3: z = pooled*a + c, then z @ W^T + b. One wave per batch row.
__global__ __launch_bounds__(64) void head_kernel(const float* __restrict__ pooled,
                                                  const float* __restrict__ a,
                                                  const float* __restrict__ c,
                                                  const float* __restrict__ Wl,
                                                  const float* __restrict__ bl,
                                                  float* __restrict__ out) {
  const int row = blockIdx.x;     // 0..1023
  const int lane = threadIdx.x;   // 0..63
  const float* pr = pooled + (size_t)row * 576;
  float acc0 = 0, acc1 = 0, acc2 = 0, acc3 = 0, acc4 = 0;
  float acc5 = 0, acc6 = 0, acc7 = 0, acc8 = 0, acc9 = 0;
#pragma unroll
  for (int j = 0; j < 9; ++j) {
    const int k = lane + 64 * j;
    const float z = fmaf(pr[k], a[k], c[k]);
    acc0 = fmaf(z, Wl[0 * 576 + k], acc0);
    acc1 = fmaf(z, Wl[1 * 576 + k], acc1);
    acc2 = fmaf(z, Wl[2 * 576 + k], acc2);
    acc3 = fmaf(z, Wl[3 * 576 + k], acc3);
    acc4 = fmaf(z, Wl[4 * 576 + k], acc4);
    acc5 = fmaf(z, Wl[5 * 576 + k], acc5);
    acc6 = fmaf(z, Wl[6 * 576 + k], acc6);
    acc7 = fmaf(z, Wl[7 * 576 + k], acc7);
    acc8 = fmaf(z, Wl[8 * 576 + k], acc8);
    acc9 = fmaf(z, Wl[9 * 576 + k], acc9);
  }
#pragma unroll
  for (int m = 1; m < 64; m <<= 1) {
    acc0 += __shfl_xor(acc0, m); acc1 += __shfl_xor(acc1, m);
    acc2 += __shfl_xor(acc2, m); acc3 += __shfl_xor(acc3, m);
    acc4 += __shfl_xor(acc4, m); acc5 += __shfl_xor(acc5, m);
    acc6 += __shfl_xor(acc6, m); acc7 += __shfl_xor(acc7, m);
    acc8 += __shfl_xor(acc8, m); acc9 += __shfl_xor(acc9, m);
  }
  if (lane == 0) {
    float* o = out + (size_t)row * 10;
    o[0] = acc0 + bl[0]; o[1] = acc1 + bl[1]; o[2] = acc2 + bl[2];
    o[3] = acc3 + bl[3]; o[4] = acc4 + bl[4]; o[5] = acc5 + bl[5];
    o[6] = acc6 + bl[6]; o[7] = acc7 + bl[7]; o[8] = acc8 + bl[8];
    o[9] = acc9 + bl[9];
  }
}

extern "C" void kernel_launch(void* const* d_in, const int* in_sizes, int n_in,
                              void* d_out, int out_size, void* d_ws, size_t ws_size,
                              hipStream_t stream) {
  const float* x     = (const float*)d_in[0];
  const float* gamma = (const float*)d_in[1];
  const float* beta  = (const float*)d_in[2];
  const float* Wl    = (const float*)d_in[3];
  const float* bl    = (const float*)d_in[4];
  float* out = (float*)d_out;

  float* pooled = (float*)d_ws;            // 1024*576 floats
  float* a = pooled + 576 * 1024;          // 576 floats
  float* c = a + 576;                      // 576 floats

  zpool_kernel<<<3072, 256, 0, stream>>>(x, pooled);
  bn_stats_kernel<<<576, 256, 0, stream>>>(pooled, gamma, beta, a, c);
  head_kernel<<<1024, 64, 0, stream>>>(pooled, a, c, Wl, bl, out);
}

// Round 13
// 35.811 us; speedup vs baseline: 1.1969x; 1.1969x over previous
//
#include <hip/hip_runtime.h>
#include <math.h>

#define PI_F 3.14159265358979323846f
typedef float floatx4 __attribute__((ext_vector_type(4)));

// ---- 8-lane sum reduction (contiguous lanes 8q..8q+7), pure VALU DPP ----
// quad_perm xor1 (0xB1), quad_perm xor2 (0x4E), then row_shl:4 (0x104):
// lanes s=0..3 receive s+4's quad-sum (same 8-group; bound_ctrl zero-fills).
// Valid result at s==0 (and s=1..3).
template <int CTRL>
__device__ __forceinline__ float dpp_addf(float v) {
  int p = __builtin_amdgcn_update_dpp(0, __float_as_int(v), CTRL, 0xF, 0xF, true);
  return v + __int_as_float(p);
}
__device__ __forceinline__ float red8(float v) {
  v = dpp_addf<0xB1>(v);
  v = dpp_addf<0x4E>(v);
  v = dpp_addf<0x104>(v);   // row_shl:4
  return v;
}

// Kernel 1: Zernike pooling, register-resident (NO LDS staging).
// One block per (batch, rank). Chunk idx in [0,2048) = (pixel p = idx>>3,
// channel-quad cq = idx&7). Lane mapping: s = lane&7, cq = lane>>3,
// idx(i) = (i*4+w)*64 + s*8 + cq  -> per wave-instr the 64 idx are CONSECUTIVE
// (8 pixels x 128B segments, same coalescing as the R11 staging, proven).
// Thread owns 8 pixels p = 32i+8w+s of one cq: x-col = (8w+s)&15 const,
// h = 2i + (w>>1). Channel-group = 8 contiguous lanes -> red8 is DPP-only.
__global__ __launch_bounds__(256) void zpool_kernel(const float* __restrict__ x,
                                                    float* __restrict__ pooled) {
  const int blk = blockIdx.x;              // 0..3071
  const int b = blk / 3;
  const int rank = blk - b * 3;
  const floatx4* __restrict__ src4 =
      reinterpret_cast<const floatx4*>(x) + (size_t)b * 6144 + rank * 8;

  const int t = threadIdx.x;
  const int lane = t & 63;
  const int w = t >> 6;                    // wave 0..3
  const int cq = lane >> 3;                // channel quad 0..7 (8 contiguous lanes)
  const int s = lane & 7;                  // pixel-slot within group
  const int xcol = (8 * w + s) & 15;
  const int hoff = w >> 1;                 // 0 or 1
  const float X = -1.0f + (float)xcol * (2.0f / 15.0f);   // thread-constant

  __shared__ float p1[4][8][12];
  __shared__ float cxy[8][8];
  __shared__ float p2[4][8][40];

  // Load 8 float4 chunks (one cq, pixels p = 32i + 8w + s) into registers.
  floatx4 f[8];
#pragma unroll
  for (int i = 0; i < 8; ++i)
    f[i] = src4[(32 * i + 8 * w + s) * 24 + cq];

  // ---- Pass 1: centroid sums (per channel component) ----
  floatx4 s0v = {0, 0, 0, 0}, syv = {0, 0, 0, 0};
#pragma unroll
  for (int i = 0; i < 8; ++i) {
    const float Y = -1.0f + (float)(2 * i + hoff) * (2.0f / 15.0f);
    s0v += f[i];
    syv += f[i] * Y;
  }
  floatx4 sxv = s0v * X;                   // X thread-constant
#pragma unroll
  for (int c = 0; c < 4; ++c) {
    s0v[c] = red8(s0v[c]);
    sxv[c] = red8(sxv[c]);
    syv[c] = red8(syv[c]);
  }
  if (s == 0) {
#pragma unroll
    for (int c = 0; c < 4; ++c) {
      p1[w][cq][c] = s0v[c];
      p1[w][cq][4 + c] = sxv[c];
      p1[w][cq][8 + c] = syv[c];
    }
  }
  __syncthreads();
  if (t < 8) {                             // leader for cq = t
#pragma unroll
    for (int c = 0; c < 4; ++c) {
      float S0 = 0.0f, SX = 0.0f, SY = 0.0f;
#pragma unroll
      for (int w2 = 0; w2 < 4; ++w2) {
        S0 += p1[w2][t][c];
        SX += p1[w2][t][4 + c];
        SY += p1[w2][t][8 + c];
      }
      const float inv = 1.0f / (S0 + 1e-6f);
      cxy[t][c] = SX * inv;
      cxy[t][4 + c] = SY * inv;
    }
  }
  __syncthreads();
  floatx4 cx, cy;
#pragma unroll
  for (int c = 0; c < 4; ++c) { cx[c] = cxy[cq][c]; cy[c] = cxy[cq][4 + c]; }

  const floatx4 Xs = X - cx;
  const floatx4 Xs2 = Xs * Xs;
  const floatx4 Xs3 = Xs2 * Xs;
  const floatx4 lim = 1.0f - Xs2;          // mask: Ys^2 <= 1 - Xs^2

  // ---- Pass 2: moments m_j = sum g * Ys^j from registers ----
  floatx4 m0 = {0,0,0,0}, m1 = {0,0,0,0}, m2 = {0,0,0,0}, m3 = {0,0,0,0};
#pragma unroll
  for (int i = 0; i < 8; ++i) {
    const float Y = -1.0f + (float)(2 * i + hoff) * (2.0f / 15.0f);
    const floatx4 Ys = Y - cy;
    const floatx4 Ys2 = Ys * Ys;
    floatx4 g;
#pragma unroll
    for (int c = 0; c < 4; ++c) g[c] = (Ys2[c] <= lim[c]) ? f[i][c] : 0.0f;
    const floatx4 gy = g * Ys;
    m0 += g;
    m1 += gy;
    m2 += gy * Ys;
    m3 += gy * Ys2;
  }

  // S_ij = Xs^i * m_j partials (thread-local), then 8-lane reduce.
  floatx4 S[10];
  S[0] = m0;        S[1] = Xs * m0;  S[2] = Xs2 * m0; S[3] = Xs3 * m0;
  S[4] = m1;        S[5] = Xs * m1;  S[6] = Xs2 * m1;
  S[7] = m2;        S[8] = Xs * m2;  S[9] = m3;
#pragma unroll
  for (int v = 0; v < 10; ++v)
#pragma unroll
    for (int c = 0; c < 4; ++c) S[v][c] = red8(S[v][c]);

  if (s == 0) {
#pragma unroll
    for (int v = 0; v < 10; ++v)
#pragma unroll
      for (int c = 0; c < 4; ++c) p2[w][cq][v * 4 + c] = S[v][c];
  }
  __syncthreads();

  if (t < 32) {                            // leader per channel ch = t
    const int fcq = t >> 2, comp = t & 3;
    float T[10];
#pragma unroll
    for (int v = 0; v < 10; ++v) {
      float acc = 0.0f;
#pragma unroll
      for (int w2 = 0; w2 < 4; ++w2) acc += p2[w2][fcq][v * 4 + comp];
      T[v] = acc;
    }
    const float S00 = T[0], S10 = T[1], S20 = T[2], S30 = T[3];
    const float S01 = T[4], S11 = T[5], S21 = T[6];
    const float S02 = T[7], S12 = T[8], S03 = T[9];
    const float a0 = S00;
    const float a1 = S10, b1 = S01;
    const float a2 = 2.0f * (S20 + S02) - S00;
    const float a3 = S20 - S02, b3 = 2.0f * S11;
    const float a4 = 3.0f * (S30 + S12) - 2.0f * S10;
    const float b4 = 3.0f * (S21 + S03) - 2.0f * S01;
    const float a5 = S30 - 3.0f * S12;
    const float b5 = 3.0f * S21 - S03;
    float* po = pooled + (size_t)b * 576 + rank * 192 + t;
    const float INV = 1.0f / 65536.0f;     // (1/256)^2 for the means
    po[0]   = (1.0f / PI_F) * sqrtf(a0 * a0 * INV + 1e-12f);
    po[32]  = (2.0f / PI_F) * sqrtf(fmaf(a1, a1, b1 * b1) * INV + 1e-12f);
    po[64]  = (3.0f / PI_F) * sqrtf(a2 * a2 * INV + 1e-12f);
    po[96]  = (3.0f / PI_F) * sqrtf(fmaf(a3, a3, b3 * b3) * INV + 1e-12f);
    po[128] = (4.0f / PI_F) * sqrtf(fmaf(a4, a4, b4 * b4) * INV + 1e-12f);
    po[160] = (4.0f / PI_F) * sqrtf(fmaf(a5, a5, b5 * b5) * INV + 1e-12f);
  }
}

// Kernel 2: batch-norm stats per feature; fold into scale a and shift c.
// (576-block version -- part of all winning packages; unchanged)
__global__ __launch_bounds__(256) void bn_stats_kernel(const float* __restrict__ pooled,
                                                       const float* __restrict__ gamma,
                                                       const float* __restrict__ beta,
                                                       float* __restrict__ a,
                                                       float* __restrict__ c) {
  const int f = blockIdx.x;   // 0..575
  const int t = threadIdx.x;  // 256
  float s = 0.0f, sq = 0.0f;
#pragma unroll
  for (int j = 0; j < 4; ++j) {
    const float v = pooled[(size_t)(t + 256 * j) * 576 + f];
    s += v;
    sq = fmaf(v, v, sq);
  }
#pragma unroll
  for (int m = 1; m < 64; m <<= 1) {
    s += __shfl_xor(s, m);
    sq += __shfl_xor(sq, m);
  }
  __shared__ float ls[8];
  const int w = t >> 6;
  if ((t & 63) == 0) { ls[w * 2] = s; ls[w * 2 + 1] = sq; }
  __syncthreads();
  if (t == 0) {
    s = ls[0] + ls[2] + ls[4] + ls[6];
    sq = ls[1] + ls[3] + ls[5] + ls[7];
    const float mean = s * (1.0f / 1024.0f);
    const float var = fmaf(-mean, mean, sq * (1.0f / 1024.0f));  // biased var
    const float istd = rsqrtf(var + 1e-5f);
    const float av = gamma[f] * istd;
    a[f] = av;
    c[f] = fmaf(-mean, av, beta[f]);
  }
}

// Kernel 3: z = pooled*a + c, then z @ W^T + b. One wave per batch row.
__global__ __launch_bounds__(64) void head_kernel(const float* __restrict__ pooled,
                                                  const float* __restrict__ a,
                                                  const float* __restrict__ c,
                                                  const float* __restrict__ Wl,
                                                  const float* __restrict__ bl,
                                                  float* __restrict__ out) {
  const int row = blockIdx.x;     // 0..1023
  const int lane = threadIdx.x;   // 0..63
  const float* pr = pooled + (size_t)row * 576;
  float acc0 = 0, acc1 = 0, acc2 = 0, acc3 = 0, acc4 = 0;
  float acc5 = 0, acc6 = 0, acc7 = 0, acc8 = 0, acc9 = 0;
#pragma unroll
  for (int j = 0; j < 9; ++j) {
    const int k = lane + 64 * j;
    const float z = fmaf(pr[k], a[k], c[k]);
    acc0 = fmaf(z, Wl[0 * 576 + k], acc0);
    acc1 = fmaf(z, Wl[1 * 576 + k], acc1);
    acc2 = fmaf(z, Wl[2 * 576 + k], acc2);
    acc3 = fmaf(z, Wl[3 * 576 + k], acc3);
    acc4 = fmaf(z, Wl[4 * 576 + k], acc4);
    acc5 = fmaf(z, Wl[5 * 576 + k], acc5);
    acc6 = fmaf(z, Wl[6 * 576 + k], acc6);
    acc7 = fmaf(z, Wl[7 * 576 + k], acc7);
    acc8 = fmaf(z, Wl[8 * 576 + k], acc8);
    acc9 = fmaf(z, Wl[9 * 576 + k], acc9);
  }
#pragma unroll
  for (int m = 1; m < 64; m <<= 1) {
    acc0 += __shfl_xor(acc0, m); acc1 += __shfl_xor(acc1, m);
    acc2 += __shfl_xor(acc2, m); acc3 += __shfl_xor(acc3, m);
    acc4 += __shfl_xor(acc4, m); acc5 += __shfl_xor(acc5, m);
    acc6 += __shfl_xor(acc6, m); acc7 += __shfl_xor(acc7, m);
    acc8 += __shfl_xor(acc8, m); acc9 += __shfl_xor(acc9, m);
  }
  if (lane == 0) {
    float* o = out + (size_t)row * 10;
    o[0] = acc0 + bl[0]; o[1] = acc1 + bl[1]; o[2] = acc2 + bl[2];
    o[3] = acc3 + bl[3]; o[4] = acc4 + bl[4]; o[5] = acc5 + bl[5];
    o[6] = acc6 + bl[6]; o[7] = acc7 + bl[7]; o[8] = acc8 + bl[8];
    o[9] = acc9 + bl[9];
  }
}

extern "C" void kernel_launch(void* const* d_in, const int* in_sizes, int n_in,
                              void* d_out, int out_size, void* d_ws, size_t ws_size,
                              hipStream_t stream) {
  const float* x     = (const float*)d_in[0];
  const float* gamma = (const float*)d_in[1];
  const float* beta  = (const float*)d_in[2];
  const float* Wl    = (const float*)d_in[3];
  const float* bl    = (const float*)d_in[4];
  float* out = (float*)d_out;

  float* pooled = (float*)d_ws;            // 1024*576 floats
  float* a = pooled + 576 * 1024;          // 576 floats
  float* c = a + 576;                      // 576 floats

  zpool_kernel<<<3072, 256, 0, stream>>>(x, pooled);
  bn_stats_kernel<<<576, 256, 0, stream>>>(pooled, gamma, beta, a, c);
  head_kernel<<<1024, 64, 0, stream>>>(pooled, a, c, Wl, bl, out);
}

// Round 14
// 34.029 us; speedup vs baseline: 1.2596x; 1.0524x over previous
//
#include <hip/hip_runtime.h>
#include <math.h>

#define PI_F 3.14159265358979323846f
typedef float floatx4 __attribute__((ext_vector_type(4)));

// ---- DPP reduction ladders (HW-validated R7/R8/R11/R13) ----
template <int CTRL>
__device__ __forceinline__ float dpp_addf(float v) {
  int p = __builtin_amdgcn_update_dpp(0, __float_as_int(v), CTRL, 0xF, 0xF, true);
  return v + __int_as_float(p);
}
__device__ __forceinline__ float red8(float v) {
  v = dpp_addf<0xB1>(v);
  v = dpp_addf<0x4E>(v);
  v = dpp_addf<0x104>(v);   // row_shl:4
  return v;
}
__device__ __forceinline__ float red16(float v) {
  v = dpp_addf<0xB1>(v);    // quad_perm xor1
  v = dpp_addf<0x4E>(v);    // quad_perm xor2
  v = dpp_addf<0x124>(v);   // row_ror:4
  v = dpp_addf<0x128>(v);   // row_ror:8
  return v;
}
// 64-lane sum: DPP for the 16-lane part, shfl for the 16/32 crossings.
__device__ __forceinline__ float red64(float v) {
  v = red16(v);
  v += __shfl_xor(v, 16);
  v += __shfl_xor(v, 32);
  return v;
}

// Kernel 1: Zernike pooling, register-resident (NO LDS staging).
// (= round-13 best, 35.8us total; unchanged)
__global__ __launch_bounds__(256) void zpool_kernel(const float* __restrict__ x,
                                                    float* __restrict__ pooled) {
  const int blk = blockIdx.x;              // 0..3071
  const int b = blk / 3;
  const int rank = blk - b * 3;
  const floatx4* __restrict__ src4 =
      reinterpret_cast<const floatx4*>(x) + (size_t)b * 6144 + rank * 8;

  const int t = threadIdx.x;
  const int lane = t & 63;
  const int w = t >> 6;                    // wave 0..3
  const int cq = lane >> 3;                // channel quad 0..7 (8 contiguous lanes)
  const int s = lane & 7;                  // pixel-slot within group
  const int xcol = (8 * w + s) & 15;
  const int hoff = w >> 1;                 // 0 or 1
  const float X = -1.0f + (float)xcol * (2.0f / 15.0f);   // thread-constant

  __shared__ float p1[4][8][12];
  __shared__ float cxy[8][8];
  __shared__ float p2[4][8][40];

  floatx4 f[8];
#pragma unroll
  for (int i = 0; i < 8; ++i)
    f[i] = src4[(32 * i + 8 * w + s) * 24 + cq];

  // ---- Pass 1: centroid sums ----
  floatx4 s0v = {0, 0, 0, 0}, syv = {0, 0, 0, 0};
#pragma unroll
  for (int i = 0; i < 8; ++i) {
    const float Y = -1.0f + (float)(2 * i + hoff) * (2.0f / 15.0f);
    s0v += f[i];
    syv += f[i] * Y;
  }
  floatx4 sxv = s0v * X;
#pragma unroll
  for (int c = 0; c < 4; ++c) {
    s0v[c] = red8(s0v[c]);
    sxv[c] = red8(sxv[c]);
    syv[c] = red8(syv[c]);
  }
  if (s == 0) {
#pragma unroll
    for (int c = 0; c < 4; ++c) {
      p1[w][cq][c] = s0v[c];
      p1[w][cq][4 + c] = sxv[c];
      p1[w][cq][8 + c] = syv[c];
    }
  }
  __syncthreads();
  if (t < 8) {
#pragma unroll
    for (int c = 0; c < 4; ++c) {
      float S0 = 0.0f, SX = 0.0f, SY = 0.0f;
#pragma unroll
      for (int w2 = 0; w2 < 4; ++w2) {
        S0 += p1[w2][t][c];
        SX += p1[w2][t][4 + c];
        SY += p1[w2][t][8 + c];
      }
      const float inv = 1.0f / (S0 + 1e-6f);
      cxy[t][c] = SX * inv;
      cxy[t][4 + c] = SY * inv;
    }
  }
  __syncthreads();
  floatx4 cx, cy;
#pragma unroll
  for (int c = 0; c < 4; ++c) { cx[c] = cxy[cq][c]; cy[c] = cxy[cq][4 + c]; }

  const floatx4 Xs = X - cx;
  const floatx4 Xs2 = Xs * Xs;
  const floatx4 Xs3 = Xs2 * Xs;
  const floatx4 lim = 1.0f - Xs2;          // mask: Ys^2 <= 1 - Xs^2

  // ---- Pass 2: moments m_j = sum g * Ys^j ----
  floatx4 m0 = {0,0,0,0}, m1 = {0,0,0,0}, m2 = {0,0,0,0}, m3 = {0,0,0,0};
#pragma unroll
  for (int i = 0; i < 8; ++i) {
    const float Y = -1.0f + (float)(2 * i + hoff) * (2.0f / 15.0f);
    const floatx4 Ys = Y - cy;
    const floatx4 Ys2 = Ys * Ys;
    floatx4 g;
#pragma unroll
    for (int c = 0; c < 4; ++c) g[c] = (Ys2[c] <= lim[c]) ? f[i][c] : 0.0f;
    const floatx4 gy = g * Ys;
    m0 += g;
    m1 += gy;
    m2 += gy * Ys;
    m3 += gy * Ys2;
  }

  floatx4 S[10];
  S[0] = m0;        S[1] = Xs * m0;  S[2] = Xs2 * m0; S[3] = Xs3 * m0;
  S[4] = m1;        S[5] = Xs * m1;  S[6] = Xs2 * m1;
  S[7] = m2;        S[8] = Xs * m2;  S[9] = m3;
#pragma unroll
  for (int v = 0; v < 10; ++v)
#pragma unroll
    for (int c = 0; c < 4; ++c) S[v][c] = red8(S[v][c]);

  if (s == 0) {
#pragma unroll
    for (int v = 0; v < 10; ++v)
#pragma unroll
      for (int c = 0; c < 4; ++c) p2[w][cq][v * 4 + c] = S[v][c];
  }
  __syncthreads();

  if (t < 32) {
    const int fcq = t >> 2, comp = t & 3;
    float T[10];
#pragma unroll
    for (int v = 0; v < 10; ++v) {
      float acc = 0.0f;
#pragma unroll
      for (int w2 = 0; w2 < 4; ++w2) acc += p2[w2][fcq][v * 4 + comp];
      T[v] = acc;
    }
    const float S00 = T[0], S10 = T[1], S20 = T[2], S30 = T[3];
    const float S01 = T[4], S11 = T[5], S21 = T[6];
    const float S02 = T[7], S12 = T[8], S03 = T[9];
    const float a0 = S00;
    const float a1 = S10, b1 = S01;
    const float a2 = 2.0f * (S20 + S02) - S00;
    const float a3 = S20 - S02, b3 = 2.0f * S11;
    const float a4 = 3.0f * (S30 + S12) - 2.0f * S10;
    const float b4 = 3.0f * (S21 + S03) - 2.0f * S01;
    const float a5 = S30 - 3.0f * S12;
    const float b5 = 3.0f * S21 - S03;
    float* po = pooled + (size_t)b * 576 + rank * 192 + t;
    const float INV = 1.0f / 65536.0f;     // (1/256)^2 for the means
    po[0]   = (1.0f / PI_F) * sqrtf(a0 * a0 * INV + 1e-12f);
    po[32]  = (2.0f / PI_F) * sqrtf(fmaf(a1, a1, b1 * b1) * INV + 1e-12f);
    po[64]  = (3.0f / PI_F) * sqrtf(a2 * a2 * INV + 1e-12f);
    po[96]  = (3.0f / PI_F) * sqrtf(fmaf(a3, a3, b3 * b3) * INV + 1e-12f);
    po[128] = (4.0f / PI_F) * sqrtf(fmaf(a4, a4, b4 * b4) * INV + 1e-12f);
    po[160] = (4.0f / PI_F) * sqrtf(fmaf(a5, a5, b5 * b5) * INV + 1e-12f);
  }
}

// Kernel 2: BN stats, float4 edition. 144 blocks x 256 thr; block owns 4
// consecutive features (one float4 per row): tx count / instr count 4x lower
// than the scalar 576-block version. Hybrid DPP+shfl wave reduce.
__global__ __launch_bounds__(256) void bn_stats_kernel(const float* __restrict__ pooled,
                                                       const float* __restrict__ gamma,
                                                       const float* __restrict__ beta,
                                                       float* __restrict__ a,
                                                       float* __restrict__ c) {
  const int f0 = blockIdx.x * 4;           // 0,4,...,572
  const int t = threadIdx.x;               // 256
  const floatx4* __restrict__ p =
      reinterpret_cast<const floatx4*>(pooled + f0);   // row stride 144 float4
  floatx4 s = {0, 0, 0, 0}, q = {0, 0, 0, 0};
#pragma unroll
  for (int j = 0; j < 4; ++j) {
    const floatx4 v = p[(size_t)(t + 256 * j) * 144];
    s += v;
    q += v * v;
  }
#pragma unroll
  for (int cc = 0; cc < 4; ++cc) {
    s[cc] = red64(s[cc]);
    q[cc] = red64(q[cc]);
  }
  __shared__ float ls[4][8];
  const int w = t >> 6;
  if ((t & 63) == 0) {
#pragma unroll
    for (int cc = 0; cc < 4; ++cc) { ls[w][cc] = s[cc]; ls[w][4 + cc] = q[cc]; }
  }
  __syncthreads();
  if (t < 4) {                             // thread t -> feature f0+t
    float S = 0.0f, Q = 0.0f;
#pragma unroll
    for (int i = 0; i < 4; ++i) { S += ls[i][t]; Q += ls[i][4 + t]; }
    const float mean = S * (1.0f / 1024.0f);
    const float var = fmaf(-mean, mean, Q * (1.0f / 1024.0f));  // biased var
    const float istd = rsqrtf(var + 1e-5f);
    const float av = gamma[f0 + t] * istd;
    a[f0 + t] = av;
    c[f0 + t] = fmaf(-mean, av, beta[f0 + t]);
  }
}

// Kernel 3: z = pooled*a + c, then z @ W^T + b. One wave per batch row.
// Reduction now hybrid DPP+shfl: LDS-pipe ops/wave 60 -> 20.
__global__ __launch_bounds__(64) void head_kernel(const float* __restrict__ pooled,
                                                  const float* __restrict__ a,
                                                  const float* __restrict__ c,
                                                  const float* __restrict__ Wl,
                                                  const float* __restrict__ bl,
                                                  float* __restrict__ out) {
  const int row = blockIdx.x;     // 0..1023
  const int lane = threadIdx.x;   // 0..63
  const float* pr = pooled + (size_t)row * 576;
  float acc0 = 0, acc1 = 0, acc2 = 0, acc3 = 0, acc4 = 0;
  float acc5 = 0, acc6 = 0, acc7 = 0, acc8 = 0, acc9 = 0;
#pragma unroll
  for (int j = 0; j < 9; ++j) {
    const int k = lane + 64 * j;
    const float z = fmaf(pr[k], a[k], c[k]);
    acc0 = fmaf(z, Wl[0 * 576 + k], acc0);
    acc1 = fmaf(z, Wl[1 * 576 + k], acc1);
    acc2 = fmaf(z, Wl[2 * 576 + k], acc2);
    acc3 = fmaf(z, Wl[3 * 576 + k], acc3);
    acc4 = fmaf(z, Wl[4 * 576 + k], acc4);
    acc5 = fmaf(z, Wl[5 * 576 + k], acc5);
    acc6 = fmaf(z, Wl[6 * 576 + k], acc6);
    acc7 = fmaf(z, Wl[7 * 576 + k], acc7);
    acc8 = fmaf(z, Wl[8 * 576 + k], acc8);
    acc9 = fmaf(z, Wl[9 * 576 + k], acc9);
  }
  acc0 = red64(acc0); acc1 = red64(acc1); acc2 = red64(acc2);
  acc3 = red64(acc3); acc4 = red64(acc4); acc5 = red64(acc5);
  acc6 = red64(acc6); acc7 = red64(acc7); acc8 = red64(acc8);
  acc9 = red64(acc9);
  if (lane == 0) {
    float* o = out + (size_t)row * 10;
    o[0] = acc0 + bl[0]; o[1] = acc1 + bl[1]; o[2] = acc2 + bl[2];
    o[3] = acc3 + bl[3]; o[4] = acc4 + bl[4]; o[5] = acc5 + bl[5];
    o[6] = acc6 + bl[6]; o[7] = acc7 + bl[7]; o[8] = acc8 + bl[8];
    o[9] = acc9 + bl[9];
  }
}

extern "C" void kernel_launch(void* const* d_in, const int* in_sizes, int n_in,
                              void* d_out, int out_size, void* d_ws, size_t ws_size,
                              hipStream_t stream) {
  const float* x     = (const float*)d_in[0];
  const float* gamma = (const float*)d_in[1];
  const float* beta  = (const float*)d_in[2];
  const float* Wl    = (const float*)d_in[3];
  const float* bl    = (const float*)d_in[4];
  float* out = (float*)d_out;

  float* pooled = (float*)d_ws;            // 1024*576 floats
  float* a = pooled + 576 * 1024;          // 576 floats
  float* c = a + 576;                      // 576 floats

  zpool_kernel<<<3072, 256, 0, stream>>>(x, pooled);
  bn_stats_kernel<<<144, 256, 0, stream>>>(pooled, gamma, beta, a, c);
  head_kernel<<<1024, 64, 0, stream>>>(pooled, a, c, Wl, bl, out);
}